// Round 12
// baseline (180.494 us; speedup 1.0000x reference)
//
#include <hip/hip_runtime.h>
#include <hip/hip_bf16.h>
#include <cstddef>

#define NB 2048
#define TENC 168
#define TPRED 24

typedef _Float16 h8 __attribute__((ext_vector_type(8)));
typedef _Float16 h4 __attribute__((ext_vector_type(4)));
typedef float f4v __attribute__((ext_vector_type(4)));

#define MFMA16(a, b, c)    __builtin_amdgcn_mfma_f32_16x16x32_f16((a), (b), (c), 0, 0, 0)
#define MFMA16K16(a, b, c) __builtin_amdgcn_mfma_f32_16x16x16f16((a), (b), (c), 0, 0, 0)

__device__ __forceinline__ float gate_fast(float a, float g) {
  a = fminf(a, 15.0f);
  const float e2a = __builtin_amdgcn_exp2f(a * 2.88539008177793f);    // e^(2a)
  const float eg  = __builtin_amdgcn_exp2f(g * -1.44269504088896f);   // e^(-g)
  return (e2a - 1.0f) * __builtin_amdgcn_rcpf((e2a + 1.0f) * (1.0f + eg));
}
__device__ __forceinline__ float tanh_fast(float u) {
  const float e2 = __builtin_amdgcn_exp2f(fminf(u, 15.0f) * 2.88539008177793f);
  return (e2 - 1.0f) * __builtin_amdgcn_rcpf(e2 + 1.0f);
}
__device__ __forceinline__ h8 cvt8(const f4v a, const f4v b) {
  h8 r;
  #pragma unroll
  for (int u = 0; u < 4; ++u) { r[u] = (_Float16)a[u]; r[u + 4] = (_Float16)b[u]; }
  return r;
}

// Single-writer monotonic flag; tight spin (flags are slack-side by design).
__device__ __forceinline__ void pollge(volatile int* f, int tgt) {
  int guard = 0;
  while (*f < tgt) { if (++guard > 2000000) break; }
  asm volatile("" ::: "memory");
}
// Publish: drain own DS ops, then lane 0 writes the flag.
#define FLAG_SET(p, v)                                      \
  do {                                                      \
    asm volatile("s_waitcnt lgkmcnt(0)" ::: "memory");      \
    if (ln == 0) *(volatile int*)(p) = (v);                 \
  } while (0)

// ---------------------------------------------------------------------------
// Phase 1 (round 12 = round 11 + builtin-name fix): 3-wave asymmetric
// pipeline, producer never blocks. 128 blocks x 192 threads; 16 elements.
// P  (w0): per layer: S(l,t) read (b128x8, C1-precomputed) || gA read ->
//          Z += gated@W43 (8 tiles,16 MFMA) -> gate(Z+S) -> g16v -> pflag.
//          Step top: Z_0 = x@W3. Only always-ready single-flag polls.
// C1 (w1): S(l,t+1) = state@W2 + b2 (f32 [l][c][el], b128 write & read),
//          one step ahead; WAR-gated on pflag (slack).
// C2 (w2): lagged out-GEMM (skip->skl LDS, res->x->ring), coalesced b128
//          skbuf flush per step, embed(t+1) via 16x16x16 MFMA, flags e/c2/l0.
// Flags: pflag=6t+l+1, sflag=6t+l+1 (S(l,t) written), eflag=t+1 (x(t) ready),
//        c2flag=t+1 (C2 done step t), c2l0=t+1 (ring slot0 for t+1 written).
// k-mapping k = hi*32 + q*8 + j (K=16: q*4+j) consistent for all A/B frags.
// C/D: col = lane&15, row = (lane>>4)*4 + reg (verified m89).
// ---------------------------------------------------------------------------
__global__ __launch_bounds__(192, 1) void dec_phase1(
    const float* __restrict__ feat,    // [2048][24][15]
    const float* __restrict__ dinit,   // [2048][1]
    const float* __restrict__ enc,     // [6][2048][168][64]
    const float* __restrict__ W1,      // [16][64]
    const float* __restrict__ b1,      // [64]
    const float* __restrict__ W2,      // [64][128]
    const float* __restrict__ b2,      // [128]
    const float* __restrict__ W3,      // [64][128]
    const float* __restrict__ W4,      // [64][128]
    const float* __restrict__ b4,      // [128]
    _Float16* __restrict__ skbuf,      // [2048*24][384] f16
    int t_steps)
{
  __shared__ _Float16 ring[23][16][72];   // 52.9 KB dilation rings / enc tails
  __shared__ float    S32[6][128][16];    // 49.2 KB S = state@W2+b2, [l][c][el]
  __shared__ _Float16 g16v[2][6][16][72]; // 27.6 KB gated [step-parity][layer]
  __shared__ _Float16 xf16[16][72];       //  2.3 KB x(t) [el][k]
  __shared__ _Float16 skl[16][392];       // 12.5 KB skip staging
  __shared__ int      flg[8];             // 0:p 1:s 2:e 3:c2 4:c2l0

  const int tid = threadIdx.x;
  const int w   = tid >> 6;
  const int ln  = tid & 63;
  const int i   = ln & 15;
  const int q   = ln >> 4;
  const int q8  = q * 8;
  const int e0  = blockIdx.x * 16;

  // ---- prologue 1: stage W3 / W4res f32 in ring region ----
  float* W3s  = (float*)&ring[0][0][0];   // [64][128] 32 KB
  float* W4rs = W3s + 64 * 128;           // [64][64]  16 KB
  for (int idx = tid; idx < 2048; idx += 192)
    ((float4*)W3s)[idx] = ((const float4*)W3)[idx];
  for (int idx = tid; idx < 1024; idx += 192) {
    const int row = idx >> 4, seg = idx & 15;
    *(float4*)&W4rs[row * 64 + seg * 4] = *(const float4*)&W4[row * 128 + 64 + seg * 4];
  }
  __syncthreads();

  // ---- prologue 2: W43 = W4res @ W3 (f16 [64][136]) in S32 region ----
  _Float16* W43h = (_Float16*)&S32[0][0][0];
  for (int idx = tid; idx < 512; idx += 192) {
    const int c = idx & 127, k0 = (idx >> 7) << 4;
    float acc[16];
    #pragma unroll
    for (int r = 0; r < 16; ++r) acc[r] = 0.0f;
    for (int m = 0; m < 64; ++m) {
      const float w3v = W3s[m * 128 + c];
      #pragma unroll
      for (int r = 0; r < 16; ++r) acc[r] += W4rs[(k0 + r) * 64 + m] * w3v;
    }
    #pragma unroll
    for (int r = 0; r < 16; ++r) W43h[(k0 + r) * 136 + c] = (_Float16)acc[r];
  }
  __syncthreads();

  // ---- prologue 3: role weight fragments (shared register arrays) ----
  // P : BW=W43 (8 tiles), BX=W3 (8 tiles)
  // C1: BW=W2  (8 tiles), bias[s]=b2[16s+i]
  // C2: BW[0..3]=W4 skip, BW[4..7]=W4 res, bias=b4; W1B h4, b1v, iniv
  h8 BW[8][2], BX[8][2];
  float bias[8];
  h4 W1B[4];
  float b1v[4] = {0, 0, 0, 0};
  float iniv = 0.f;
  if (w == 0) {
    #pragma unroll
    for (int s = 0; s < 8; ++s)
      #pragma unroll
      for (int hi = 0; hi < 2; ++hi)
        #pragma unroll
        for (int j = 0; j < 8; ++j) {
          const int k = hi * 32 + q8 + j;
          BW[s][hi][j] = W43h[k * 136 + 16 * s + i];
          BX[s][hi][j] = (_Float16)W3s[k * 128 + 16 * s + i];
        }
  } else if (w == 1) {
    #pragma unroll
    for (int s = 0; s < 8; ++s) {
      #pragma unroll
      for (int hi = 0; hi < 2; ++hi)
        #pragma unroll
        for (int j = 0; j < 8; ++j)
          BW[s][hi][j] = (_Float16)W2[(hi * 32 + q8 + j) * 128 + 16 * s + i];
      bias[s] = b2[16 * s + i];
    }
  } else {
    #pragma unroll
    for (int s = 0; s < 4; ++s) {
      #pragma unroll
      for (int hi = 0; hi < 2; ++hi)
        #pragma unroll
        for (int j = 0; j < 8; ++j) {
          const int k = hi * 32 + q8 + j;
          BW[s][hi][j]     = (_Float16)W4[k * 128 + 16 * s + i];        // skip
          BW[4 + s][hi][j] = (_Float16)W4[k * 128 + 64 + 16 * s + i];   // res
        }
      bias[s]     = b4[16 * s + i];
      bias[4 + s] = b4[64 + 16 * s + i];
      #pragma unroll
      for (int j = 0; j < 4; ++j)
        W1B[s][j] = (_Float16)W1[(q * 4 + j) * 64 + 16 * s + i];
      b1v[s] = b1[16 * s + i];
    }
    iniv = dinit[e0 + i];
  }
  __syncthreads();   // W3s/W43h consumed

  // ---- prologue 4: ring preload (enc tails l<=3; overwrites W3s) ----
  for (int idx = tid; idx < 1920; idx += 192) {
    const int c = idx & 7, el = (idx >> 3) & 15, s = idx >> 7;
    int l, j;
    if (s == 0)      { l = 0; j = 0; }
    else if (s < 3)  { l = 1; j = s - 1; }
    else if (s < 7)  { l = 2; j = s - 3; }
    else             { l = 3; j = s - 7; }
    const int d = 1 << l;
    const float* ep = enc + (((size_t)l * NB + e0 + el) * TENC + (TENC + j - d)) * 64 + c * 8;
    h8 hv;
    #pragma unroll
    for (int u = 0; u < 8; ++u) hv[u] = (_Float16)ep[u];
    *(h8*)&ring[s][el][c * 8] = hv;
  }
  if (tid < 8) flg[tid] = 0;
  __syncthreads();   // LAST barrier; flag sync only from here

  if (w == 0) {
    // ===================== PRODUCER =====================
    f4v Z[8], Sv[8];
    for (int t = 0; t < t_steps; ++t) {
      pollge(&flg[2], t + 1);       // x(t) embedded
      pollge(&flg[3], t - 1);       // g16v parity free (2-step slack)
      // ---- layer 0: Z_0 = x @ W3 ; dc_0 = Z_0 + S_0 ----
      pollge(&flg[1], 6 * t + 1);
      #pragma unroll
      for (int s = 0; s < 8; ++s) Sv[s] = *(const f4v*)&S32[0][16 * s + i][4 * q];
      const h8 a2 = *(const h8*)&xf16[i][q8];
      const h8 a3 = *(const h8*)&xf16[i][32 + q8];
      #pragma unroll
      for (int s = 0; s < 8; ++s) {
        f4v z = {0, 0, 0, 0};
        z = MFMA16(a2, BX[s][0], z);
        z = MFMA16(a3, BX[s][1], z);
        Z[s] = z;
      }
      #pragma unroll
      for (int s = 0; s < 4; ++s)
        #pragma unroll
        for (int r = 0; r < 4; ++r)
          g16v[t & 1][0][4 * q + r][16 * s + i] = (_Float16)gate_fast(
              Z[s][r] + Sv[s][r], Z[s + 4][r] + Sv[s + 4][r]);
      FLAG_SET(&flg[0], 6 * t + 1);

      for (int l = 1; l < 6; ++l) {
        pollge(&flg[1], 6 * t + l + 1);
        #pragma unroll
        for (int s = 0; s < 8; ++s) Sv[s] = *(const f4v*)&S32[l][16 * s + i][4 * q];
        const h8 g0 = *(const h8*)&g16v[t & 1][l - 1][i][q8];
        const h8 g1 = *(const h8*)&g16v[t & 1][l - 1][i][32 + q8];
        #pragma unroll
        for (int s = 0; s < 8; ++s) {
          Z[s] = MFMA16(g0, BW[s][0], Z[s]);
          Z[s] = MFMA16(g1, BW[s][1], Z[s]);
        }
        #pragma unroll
        for (int s = 0; s < 4; ++s)
          #pragma unroll
          for (int r = 0; r < 4; ++r)
            g16v[t & 1][l][4 * q + r][16 * s + i] = (_Float16)gate_fast(
                Z[s][r] + Sv[s][r], Z[s + 4][r] + Sv[s + 4][r]);
        FLAG_SET(&flg[0], 6 * t + l + 1);
      }
    }
  } else if (w == 1) {
    // ===================== C1: S precompute =====================
    for (int tt = 0; tt < t_steps; ++tt) {
      if (tt > 0) pollge(&flg[4], tt);   // ring slot0 for step tt written
      #pragma unroll
      for (int l = 0; l < 6; ++l) {
        if (tt > 0) pollge(&flg[0], 6 * (tt - 1) + l + 1);   // S(l,tt-1) consumed
        h8 sa0, sa1;
        if (l <= 3) {
          const int d = 1 << l, slot = (d - 1) + (tt & (d - 1));
          sa0 = *(const h8*)&ring[slot][i][q8];
          sa1 = *(const h8*)&ring[slot][i][32 + q8];
        } else if (l == 4) {
          if (tt < 16) {
            const float* e4 = enc + (((size_t)4 * NB + e0 + i) * TENC + (152 + tt)) * 64 + q8;
            sa0 = cvt8(*(const f4v*)(e4), *(const f4v*)(e4 + 4));
            sa1 = cvt8(*(const f4v*)(e4 + 32), *(const f4v*)(e4 + 36));
          } else {
            const int slot = 15 + (tt & 7);
            sa0 = *(const h8*)&ring[slot][i][q8];
            sa1 = *(const h8*)&ring[slot][i][32 + q8];
          }
        } else {
          const float* e5 = enc + (((size_t)5 * NB + e0 + i) * TENC + (136 + tt)) * 64 + q8;
          sa0 = cvt8(*(const f4v*)(e5), *(const f4v*)(e5 + 4));
          sa1 = cvt8(*(const f4v*)(e5 + 32), *(const f4v*)(e5 + 36));
        }
        #pragma unroll
        for (int s = 0; s < 8; ++s) {
          f4v c = {bias[s], bias[s], bias[s], bias[s]};
          c = MFMA16(sa0, BW[s][0], c);
          c = MFMA16(sa1, BW[s][1], c);
          *(f4v*)&S32[l][16 * s + i][4 * q] = c;
        }
        FLAG_SET(&flg[1], 6 * tt + l + 1);
      }
    }
  } else {
    // ===================== C2: out / stores / ring / embed =====================
    f4v xreg[4], xregN[4];
    // embed(0)
    {
      const float* fp = feat + (size_t)(e0 + i) * TPRED * 15;
      h4 ea;
      if (q == 0) { ea[0] = (_Float16)iniv; ea[1] = (_Float16)fp[0]; ea[2] = (_Float16)fp[1]; ea[3] = (_Float16)fp[2]; }
      else { const int b = q * 4 - 1;
             ea[0] = (_Float16)fp[b]; ea[1] = (_Float16)fp[b + 1]; ea[2] = (_Float16)fp[b + 2]; ea[3] = (_Float16)fp[b + 3]; }
      #pragma unroll
      for (int s = 0; s < 4; ++s) {
        f4v c = {b1v[s], b1v[s], b1v[s], b1v[s]};
        c = MFMA16K16(ea, W1B[s], c);
        #pragma unroll
        for (int r = 0; r < 4; ++r) {
          const float xv = tanh_fast(c[r]);
          xreg[s][r] = xv;
          xf16[4 * q + r][16 * s + i] = (_Float16)xv;
        }
      }
      FLAG_SET(&flg[2], 1);
    }
    for (int t = 0; t < t_steps; ++t) {
      pollge(&flg[0], 6 * t + 1);
      // embed(t+1) early (hides under P's step t)
      if (t + 1 < t_steps) {
        const float* fp = feat + ((size_t)(e0 + i) * TPRED + (t + 1)) * 15;
        h4 ea;
        if (q == 0) { ea[0] = (_Float16)iniv; ea[1] = (_Float16)fp[0]; ea[2] = (_Float16)fp[1]; ea[3] = (_Float16)fp[2]; }
        else { const int b = q * 4 - 1;
               ea[0] = (_Float16)fp[b]; ea[1] = (_Float16)fp[b + 1]; ea[2] = (_Float16)fp[b + 2]; ea[3] = (_Float16)fp[b + 3]; }
        #pragma unroll
        for (int s = 0; s < 4; ++s) {
          f4v c = {b1v[s], b1v[s], b1v[s], b1v[s]};
          c = MFMA16K16(ea, W1B[s], c);
          #pragma unroll
          for (int r = 0; r < 4; ++r) {
            const float xv = tanh_fast(c[r]);
            xregN[s][r] = xv;
            xf16[4 * q + r][16 * s + i] = (_Float16)xv;
          }
        }
        FLAG_SET(&flg[2], t + 2);
      }
      for (int l = 0; l < 6; ++l) {
        if (l > 0) pollge(&flg[0], 6 * t + l + 1);
        const h8 g0 = *(const h8*)&g16v[t & 1][l][i][q8];
        const h8 g1 = *(const h8*)&g16v[t & 1][l][i][32 + q8];
        f4v osk[4];
        #pragma unroll
        for (int s = 0; s < 4; ++s) {
          f4v c = {bias[s], bias[s], bias[s], bias[s]};
          c = MFMA16(g0, BW[s][0], c);
          c = MFMA16(g1, BW[s][1], c);
          osk[s] = c;
        }
        #pragma unroll
        for (int s = 0; s < 4; ++s)
          #pragma unroll
          for (int r = 0; r < 4; ++r)
            skl[4 * q + r][l * 64 + 16 * s + i] = (_Float16)fmaxf(osk[s][r], 0.0f);
        if (l < 5) {
          const int d = 1 << l;
          const int slot = (l <= 3) ? (d - 1) + (t & (d - 1)) : 15 + (t & 7);
          const bool wr = (t + d) <= 23;
          #pragma unroll
          for (int s = 0; s < 4; ++s) {
            f4v c = {bias[4 + s], bias[4 + s], bias[4 + s], bias[4 + s]};
            c = MFMA16(g0, BW[4 + s][0], c);
            c = MFMA16(g1, BW[4 + s][1], c);
            #pragma unroll
            for (int r = 0; r < 4; ++r) {
              xreg[s][r] += c[r];
              if (wr) ring[slot][4 * q + r][16 * s + i] = (_Float16)xreg[s][r];
            }
          }
        }
        if (l == 0) FLAG_SET(&flg[4], t + 1);   // ring slot0 for t+1 ready
      }
      // flush skl -> skbuf (coalesced b128)
      asm volatile("s_waitcnt lgkmcnt(0)" ::: "memory");
      #pragma unroll
      for (int it = 0; it < 12; ++it) {
        const int seg = ln + 64 * it;           // 0..767
        const int el = seg / 48, c8 = seg % 48;
        const h8 v = *(const h8*)&skl[el][c8 * 8];
        *(h8*)&skbuf[((size_t)(e0 + el) * TPRED + t) * 384 + c8 * 8] = v;
      }
      FLAG_SET(&flg[3], t + 1);
      #pragma unroll
      for (int s = 0; s < 4; ++s) xreg[s] = xregN[s];
    }
  }
}

// ---------------------------------------------------------------------------
// Phase 2: y = relu( sk @ W5 + b5 ) @ W6 + b6, 49152 rows, f16 MFMA.
// 512 blocks x 96 rows; 76.5 KB LDS -> 2 blocks/CU.
// ---------------------------------------------------------------------------
__global__ __launch_bounds__(512, 1) void dec_phase2(
    const _Float16* __restrict__ skbuf,  // [49152][384] f16 (already relu'd)
    const float* __restrict__ W5,        // [384][128]
    const float* __restrict__ b5,        // [128]
    const float* __restrict__ W6,        // [128]
    const float* __restrict__ b6,        // [1]
    float* __restrict__ out)             // [49152]
{
  __shared__ _Float16 As[96][392];
  __shared__ float red[96][8];

  const int tid = threadIdx.x;
  const int w   = tid >> 6;
  const int ln  = tid & 63;
  const int i   = ln & 15;
  const int q   = ln >> 4;
  const int R0  = blockIdx.x * 96;
  const int col = 16 * w + i;

  h8 B5[12];
  #pragma unroll
  for (int kk = 0; kk < 12; ++kk)
    #pragma unroll
    for (int j = 0; j < 8; ++j)
      B5[kk][j] = (_Float16)W5[(size_t)(kk * 32 + q * 8 + j) * 128 + col];
  const float b5r = b5[col], w6r = W6[col];

  #pragma unroll
  for (int it = 0; it < 9; ++it) {
    const int idx = tid + it * 512;
    const h8 v = *(const h8*)&skbuf[(size_t)(R0 + idx / 48) * 384 + (idx % 48) * 8];
    *(h8*)&As[idx / 48][(idx % 48) * 8] = v;
  }
  __syncthreads();

  #pragma unroll
  for (int m = 0; m < 6; ++m) {
    f4v acc = {0, 0, 0, 0};
    #pragma unroll
    for (int kk = 0; kk < 12; ++kk) {
      const h8 a = *(const h8*)&As[16 * m + i][kk * 32 + q * 8];
      acc = MFMA16(a, B5[kk], acc);
    }
    float py[4];
    #pragma unroll
    for (int r = 0; r < 4; ++r)
      py[r] = fmaxf(acc[r] + b5r, 0.0f) * w6r;
    #pragma unroll
    for (int r = 0; r < 4; ++r) {
      float v = py[r];
      v += __shfl_xor(v, 1);
      v += __shfl_xor(v, 2);
      v += __shfl_xor(v, 4);
      v += __shfl_xor(v, 8);
      py[r] = v;
    }
    if (i == 0) {
      #pragma unroll
      for (int r = 0; r < 4; ++r) red[16 * m + 4 * q + r][w] = py[r];
    }
  }
  __syncthreads();

  if (tid < 96) {
    const f4v r0 = *(const f4v*)&red[tid][0];
    const f4v r1 = *(const f4v*)&red[tid][4];
    out[R0 + tid] = b6[0] + r0[0] + r0[1] + r0[2] + r0[3]
                          + r1[0] + r1[1] + r1[2] + r1[3];
  }
}

extern "C" void kernel_launch(void* const* d_in, const int* in_sizes, int n_in,
                              void* d_out, int out_size, void* d_ws, size_t ws_size,
                              hipStream_t stream) {
  const float* feat  = (const float*)d_in[0];
  const float* dinit = (const float*)d_in[1];
  const float* enc   = (const float*)d_in[2];
  const float* W1    = (const float*)d_in[3];
  const float* b1    = (const float*)d_in[4];
  const float* W2    = (const float*)d_in[5];
  const float* b2    = (const float*)d_in[6];
  const float* W3    = (const float*)d_in[7];
  const float* W4    = (const float*)d_in[8];
  const float* b4    = (const float*)d_in[9];
  const float* W5    = (const float*)d_in[10];
  const float* b5    = (const float*)d_in[11];
  const float* W6    = (const float*)d_in[12];
  const float* b6    = (const float*)d_in[13];

  float*     out   = (float*)d_out;
  _Float16*  skbuf = (_Float16*)d_ws;   // 49152*384*2 = 37.7 MB workspace

  dec_phase1<<<dim3(128), dim3(192), 0, stream>>>(
      feat, dinit, enc, W1, b1, W2, b2, W3, W4, b4, skbuf, TPRED);
  dec_phase2<<<dim3(512), dim3(512), 0, stream>>>(
      skbuf, W5, b5, W6, b6, out);
}